// Round 1
// baseline (13767.459 us; speedup 1.0000x reference)
//
#include <hip/hip_runtime.h>

// FixedFreqModel: B=512, L=2048, M=256, H=64, VOCAB=64, READ_FREQ=16.
// Strategy: one wave (64 threads) per batch element; 512 blocks, no grid sync.
//   gi = W_ih@[x;ret]+b_ih  ==  G[token] (precomputed, 64x192) + W_r@ret (once/chunk)
//   per-step work is only W_hh@h (192x64) from LDS + gate math.
// ws layout (floats):
//   kT   [B][H][M]   (transposed keys, for coalesced score loads)
//   v    [B][M][H]
//   G    [64][192]   (W_x @ embed + b_ih)
//   WPhh [16][3][64] float4  (W_hh packed: lane-consecutive)
//   WR   [16][3][64] float4  (W_ih retrieved-half packed)
//   QP   [16][64]    float4  (query_w packed)
//   KWP/VWP [16][64] float4  (key_w / val_w packed, for kv precompute)

#define B_ 512
#define L_ 2048
#define M_ 256
#define H_ 64
#define C_ 128
#define F_ 16

#define OFF_KT   0u
#define OFF_V    8388608u
#define OFF_G    16777216u
#define OFF_WPHH 16789504u
#define OFF_WR   16801792u
#define OFF_QP   16814080u
#define OFF_KWP  16818176u
#define OFF_VWP  16822272u

__device__ __forceinline__ float dot4(float4 a, float4 b) {
    return a.x*b.x + a.y*b.y + a.z*b.z + a.w*b.w;
}

// ---------------- pack weights into float4 lane-consecutive layouts ----------
__global__ void pack_weights(const float* __restrict__ w_ih,
                             const float* __restrict__ w_hh,
                             const float* __restrict__ qw,
                             const float* __restrict__ kw,
                             const float* __restrict__ vw,
                             float4* __restrict__ WPhh,
                             float4* __restrict__ WR,
                             float4* __restrict__ QP,
                             float4* __restrict__ KWP,
                             float4* __restrict__ VWP)
{
    int idx = blockIdx.x * 256 + threadIdx.x;
    if (idx < 3072) {                       // WPhh[(k4*3+g)*64+j] = w_hh[(g*64+j)][4k4..]
        int j = idx & 63, kg = idx >> 6, g = kg % 3, k4 = kg / 3;
        const float* s = w_hh + (g*64 + j)*64 + 4*k4;
        WPhh[idx] = make_float4(s[0], s[1], s[2], s[3]);
    } else if (idx < 6144) {                // WR: retrieved half of w_ih (cols 64..127)
        int i = idx - 3072;
        int j = i & 63, kg = i >> 6, g = kg % 3, k4 = kg / 3;
        const float* s = w_ih + (g*64 + j)*128 + 64 + 4*k4;
        WR[i] = make_float4(s[0], s[1], s[2], s[3]);
    } else if (idx < 7168) {                // QP[k4*64+j] = qw[j][4k4..]
        int i = idx - 6144;
        int j = i & 63, k4 = i >> 6;
        const float* s = qw + j*64 + 4*k4;
        QP[i] = make_float4(s[0], s[1], s[2], s[3]);
    } else if (idx < 8192) {
        int i = idx - 7168;
        int j = i & 63, k4 = i >> 6;
        const float* s = kw + j*64 + 4*k4;
        KWP[i] = make_float4(s[0], s[1], s[2], s[3]);
    } else if (idx < 9216) {
        int i = idx - 8192;
        int j = i & 63, k4 = i >> 6;
        const float* s = vw + j*64 + 4*k4;
        VWP[i] = make_float4(s[0], s[1], s[2], s[3]);
    }
}

// ---------------- G[v][o] = sum_k embed[v][k]*w_ih[o][k] + b_ih[o] ----------
__global__ __launch_bounds__(64) void build_G(const float* __restrict__ embed_w,
                                              const float* __restrict__ w_ih,
                                              const float* __restrict__ b_ih,
                                              float* __restrict__ G)
{
    int v = blockIdx.x, j = threadIdx.x;
    __shared__ float e_s[64];
    e_s[j] = embed_w[v*64 + j];
    __syncthreads();
    float a0 = b_ih[j], a1 = b_ih[64 + j], a2 = b_ih[128 + j];
    for (int k = 0; k < 64; ++k) {
        float e = e_s[k];
        a0 += e * w_ih[j*128 + k];
        a1 += e * w_ih[(64 + j)*128 + k];
        a2 += e * w_ih[(128 + j)*128 + k];
    }
    G[v*192 + j]       = a0;
    G[v*192 + 64 + j]  = a1;
    G[v*192 + 128 + j] = a2;
}

// ---------------- k/v precompute: one wave per (b,m) row ---------------------
__global__ __launch_bounds__(256) void compute_kv(const float* __restrict__ memory,
                                                  const float* __restrict__ key_b,
                                                  const float* __restrict__ val_b,
                                                  const float4* __restrict__ KWP,
                                                  const float4* __restrict__ VWP,
                                                  float* __restrict__ kT,
                                                  float* __restrict__ vmat)
{
    int wid = threadIdx.x >> 6;
    int o   = threadIdx.x & 63;
    int row = blockIdx.x * 4 + wid;          // row = b*256 + m
    int b = row >> 8, m = row & 255;
    __shared__ __align__(16) float mem_s[4][64];
    mem_s[wid][o] = memory[(size_t)row * 64 + o];
    __syncthreads();
    float ak = key_b[o], av = val_b[o];
    const float4* m4 = (const float4*)mem_s[wid];
#pragma unroll
    for (int k4 = 0; k4 < 16; ++k4) {
        float4 mm = m4[k4];
        ak += dot4(mm, KWP[k4*64 + o]);
        av += dot4(mm, VWP[k4*64 + o]);
    }
    kT[((size_t)b*64 + o)*256 + m] = ak;     // scattered, one-time
    vmat[(size_t)row*64 + o]       = av;     // coalesced
}

// ---------------- main recurrent kernel: 1 wave per batch element ------------
__global__ __launch_bounds__(64) void recurrent_main(
    const int*   __restrict__ seq,
    const float* __restrict__ b_hh,
    const float* __restrict__ query_b,
    const float* __restrict__ head_w,
    const float* __restrict__ head_b,
    const float* __restrict__ kT,
    const float* __restrict__ vmat,
    const float* __restrict__ G,
    const float4* __restrict__ WPhh,
    const float4* __restrict__ WR,
    const float4* __restrict__ QP,
    float* __restrict__ out)
{
    const int b = blockIdx.x;
    const int j = threadIdx.x;

    __shared__ __align__(16) float4 whh_s[16*3*64];   // 48KB
    __shared__ __align__(16) float  h_s[64];
    __shared__ __align__(16) float  ret_s[64];
    __shared__ __align__(16) float  q_s[64];
    __shared__ __align__(16) float4 p_s[64];          // 256 softmax numerators

    for (int i = j; i < 16*3*64; i += 64) whh_s[i] = WPhh[i];

    float h = 0.f;
    h_s[j] = 0.f;
    const float bhr = b_hh[j], bhz = b_hh[64 + j], bhn = b_hh[128 + j];
    const float qb  = query_b[j];
    __syncthreads();

    const float4* kT4  = (const float4*)kT + (size_t)b * 64 * 64;  // [h][j] float4
    const float*  vrow = vmat + (size_t)b * M_ * H_ + j;
    const int*    seqb = seq + (size_t)b * L_;
    const float4* h4   = (const float4*)h_s;
    const float4* r4   = (const float4*)ret_s;

    for (int c = 0; c < C_; ++c) {
        // ---- q = h @ Wq^T + qb ----
        float q = qb;
#pragma unroll
        for (int k4 = 0; k4 < 16; ++k4)
            q += dot4(h4[k4], QP[k4*64 + j]);
        q_s[j] = q;
        __syncthreads();

        // ---- scores: lane j owns m = 4j..4j+3 ----
        float4 s = make_float4(0.f, 0.f, 0.f, 0.f);
#pragma unroll 8
        for (int hh = 0; hh < 64; ++hh) {
            float qh = q_s[hh];
            float4 kk = kT4[hh*64 + j];
            s.x += qh*kk.x; s.y += qh*kk.y; s.z += qh*kk.z; s.w += qh*kk.w;
        }
        const float scale = 0.125f;
        s.x *= scale; s.y *= scale; s.z *= scale; s.w *= scale;

        // ---- softmax over 256 (wave allreduce) ----
        float mx = fmaxf(fmaxf(s.x, s.y), fmaxf(s.z, s.w));
#pragma unroll
        for (int o = 32; o > 0; o >>= 1) mx = fmaxf(mx, __shfl_xor(mx, o));
        float4 p;
        p.x = __expf(s.x - mx); p.y = __expf(s.y - mx);
        p.z = __expf(s.z - mx); p.w = __expf(s.w - mx);
        float sum = p.x + p.y + p.z + p.w;
#pragma unroll
        for (int o = 32; o > 0; o >>= 1) sum += __shfl_xor(sum, o);
        float inv = 1.f / sum;
        p_s[j] = p;
        __syncthreads();

        // ---- retrieved[o=j] = sum_m p[m] * v[b][m][j] ----
        float ret = 0.f;
        const float* ps = (const float*)p_s;
#pragma unroll 8
        for (int m = 0; m < 256; ++m)
            ret += ps[m] * vrow[m*64];
        ret *= inv;
        __syncthreads();          // everyone done with previous ret_s reads
        ret_s[j] = ret;
        __syncthreads();

        // ---- R = W_r @ ret (chunk-constant) ----
        float Rr = 0.f, Rz = 0.f, Rn = 0.f;
#pragma unroll
        for (int k4 = 0; k4 < 16; ++k4) {
            float4 rr = r4[k4];
            Rr += dot4(rr, WR[(k4*3 + 0)*64 + j]);
            Rz += dot4(rr, WR[(k4*3 + 1)*64 + j]);
            Rn += dot4(rr, WR[(k4*3 + 2)*64 + j]);
        }

        // ---- prefetch 16 tokens + their G rows ----
        int toks[F_];
#pragma unroll
        for (int t = 0; t < F_; ++t) toks[t] = seqb[c*F_ + t];
        float g0[F_], g1[F_], g2[F_];
#pragma unroll
        for (int t = 0; t < F_; ++t) {
            const float* Gp = G + toks[t]*192;
            g0[t] = Gp[j]; g1[t] = Gp[64 + j]; g2[t] = Gp[128 + j];
        }

        // ---- 16 GRU steps ----
        for (int t = 0; t < F_; ++t) {
            float ghr = bhr, ghz = bhz, ghn = bhn;
#pragma unroll
            for (int k4 = 0; k4 < 16; ++k4) {
                float4 hh = h4[k4];
                ghr += dot4(hh, whh_s[(k4*3 + 0)*64 + j]);
                ghz += dot4(hh, whh_s[(k4*3 + 1)*64 + j]);
                ghn += dot4(hh, whh_s[(k4*3 + 2)*64 + j]);
            }
            float xr = (g0[t] + Rr) + ghr;
            float xz = (g1[t] + Rz) + ghz;
            float r = 1.f / (1.f + __expf(-xr));
            float z = 1.f / (1.f + __expf(-xz));
            float xn = (g2[t] + Rn) + r * ghn;
            float e2 = __expf(-2.f * fabsf(xn));
            float n = copysignf((1.f - e2) / (1.f + e2), xn);
            h = (1.f - z) * n + z * h;
            __syncthreads();      // all lanes done reading h_s
            h_s[j] = h;
            __syncthreads();      // h_s updated for next step
        }
    }

    // ---- head: out[b][j] = h @ head_w[j] + head_b[j] ----
    float o = head_b[j];
    for (int k = 0; k < 64; ++k)
        o += h_s[k] * head_w[j*64 + k];
    out[(size_t)b*64 + j] = o;
}

extern "C" void kernel_launch(void* const* d_in, const int* in_sizes, int n_in,
                              void* d_out, int out_size, void* d_ws, size_t ws_size,
                              hipStream_t stream) {
    const int*   seq      = (const int*)  d_in[0];
    const float* memory   = (const float*)d_in[1];
    const float* embed_w  = (const float*)d_in[2];
    const float* w_ih     = (const float*)d_in[3];
    const float* w_hh     = (const float*)d_in[4];
    const float* b_ih     = (const float*)d_in[5];
    const float* b_hh     = (const float*)d_in[6];
    const float* key_w    = (const float*)d_in[7];
    const float* key_b    = (const float*)d_in[8];
    const float* val_w    = (const float*)d_in[9];
    const float* val_b    = (const float*)d_in[10];
    const float* query_w  = (const float*)d_in[11];
    const float* query_b  = (const float*)d_in[12];
    const float* head_w   = (const float*)d_in[13];
    const float* head_b   = (const float*)d_in[14];

    float* ws   = (float*)d_ws;
    float* kT   = ws + OFF_KT;
    float* vmat = ws + OFF_V;
    float* G    = ws + OFF_G;
    float4* WPhh = (float4*)(ws + OFF_WPHH);
    float4* WR   = (float4*)(ws + OFF_WR);
    float4* QP   = (float4*)(ws + OFF_QP);
    float4* KWP  = (float4*)(ws + OFF_KWP);
    float4* VWP  = (float4*)(ws + OFF_VWP);

    pack_weights<<<36, 256, 0, stream>>>(w_ih, w_hh, query_w, key_w, val_w,
                                         WPhh, WR, QP, KWP, VWP);
    build_G<<<64, 64, 0, stream>>>(embed_w, w_ih, b_ih, G);
    compute_kv<<<(B_*M_)/4, 256, 0, stream>>>(memory, key_b, val_b, KWP, VWP, kT, vmat);
    recurrent_main<<<B_, 64, 0, stream>>>(seq, b_hh, query_b, head_w, head_b,
                                          kT, vmat, G, WPhh, WR, QP, (float*)d_out);
}

// Round 2
// 6797.541 us; speedup vs baseline: 2.0254x; 2.0254x over previous
//
#include <hip/hip_runtime.h>

// FixedFreqModel: B=512, L=2048, M=256, H=64, VOCAB=64, READ_FREQ=16.
// R2: one wave per batch element; W_hh in VGPRs (192 regs); no __syncthreads
// (single-wave blocks, LDS in-order per wave); attention v-loop uses float4
// loads + shuffle reduce; tokens/G prefetched at chunk top.

#define B_ 512
#define L_ 2048
#define M_ 256
#define H_ 64
#define C_ 128
#define F_ 16

#define OFF_KT   0u
#define OFF_V    8388608u
#define OFF_G    16777216u
#define OFF_WPHH 16789504u
#define OFF_WR   16801792u
#define OFF_QP   16814080u
#define OFF_KWP  16818176u
#define OFF_VWP  16822272u

__device__ __forceinline__ float dot4(float4 a, float4 b) {
    return a.x*b.x + a.y*b.y + a.z*b.z + a.w*b.w;
}

// ---------------- pack weights into float4 lane-consecutive layouts ----------
__global__ void pack_weights(const float* __restrict__ w_ih,
                             const float* __restrict__ w_hh,
                             const float* __restrict__ qw,
                             const float* __restrict__ kw,
                             const float* __restrict__ vw,
                             float4* __restrict__ WPhh,
                             float4* __restrict__ WR,
                             float4* __restrict__ QP,
                             float4* __restrict__ KWP,
                             float4* __restrict__ VWP)
{
    int idx = blockIdx.x * 256 + threadIdx.x;
    if (idx < 3072) {                       // WPhh[(k4*3+g)*64+j] = w_hh[(g*64+j)][4k4..]
        int j = idx & 63, kg = idx >> 6, g = kg % 3, k4 = kg / 3;
        const float* s = w_hh + (g*64 + j)*64 + 4*k4;
        WPhh[idx] = make_float4(s[0], s[1], s[2], s[3]);
    } else if (idx < 6144) {                // WR: retrieved half of w_ih (cols 64..127)
        int i = idx - 3072;
        int j = i & 63, kg = i >> 6, g = kg % 3, k4 = kg / 3;
        const float* s = w_ih + (g*64 + j)*128 + 64 + 4*k4;
        WR[i] = make_float4(s[0], s[1], s[2], s[3]);
    } else if (idx < 7168) {                // QP[k4*64+j] = qw[j][4k4..]
        int i = idx - 6144;
        int j = i & 63, k4 = i >> 6;
        const float* s = qw + j*64 + 4*k4;
        QP[i] = make_float4(s[0], s[1], s[2], s[3]);
    } else if (idx < 8192) {
        int i = idx - 7168;
        int j = i & 63, k4 = i >> 6;
        const float* s = kw + j*64 + 4*k4;
        KWP[i] = make_float4(s[0], s[1], s[2], s[3]);
    } else if (idx < 9216) {
        int i = idx - 8192;
        int j = i & 63, k4 = i >> 6;
        const float* s = vw + j*64 + 4*k4;
        VWP[i] = make_float4(s[0], s[1], s[2], s[3]);
    }
}

// ---------------- G[v][o] = sum_k embed[v][k]*w_ih[o][k] + b_ih[o] ----------
__global__ __launch_bounds__(64) void build_G(const float* __restrict__ embed_w,
                                              const float* __restrict__ w_ih,
                                              const float* __restrict__ b_ih,
                                              float* __restrict__ G)
{
    int v = blockIdx.x, j = threadIdx.x;
    __shared__ float e_s[64];
    e_s[j] = embed_w[v*64 + j];
    __syncthreads();
    float a0 = b_ih[j], a1 = b_ih[64 + j], a2 = b_ih[128 + j];
    for (int k = 0; k < 64; ++k) {
        float e = e_s[k];
        a0 += e * w_ih[j*128 + k];
        a1 += e * w_ih[(64 + j)*128 + k];
        a2 += e * w_ih[(128 + j)*128 + k];
    }
    G[v*192 + j]       = a0;
    G[v*192 + 64 + j]  = a1;
    G[v*192 + 128 + j] = a2;
}

// ---------------- k/v precompute: one wave per (b,m) row ---------------------
__global__ __launch_bounds__(256) void compute_kv(const float* __restrict__ memory,
                                                  const float* __restrict__ key_b,
                                                  const float* __restrict__ val_b,
                                                  const float4* __restrict__ KWP,
                                                  const float4* __restrict__ VWP,
                                                  float* __restrict__ kT,
                                                  float* __restrict__ vmat)
{
    int wid = threadIdx.x >> 6;
    int o   = threadIdx.x & 63;
    int row = blockIdx.x * 4 + wid;          // row = b*256 + m
    int b = row >> 8, m = row & 255;
    __shared__ __align__(16) float mem_s[4][64];
    mem_s[wid][o] = memory[(size_t)row * 64 + o];
    __syncthreads();
    float ak = key_b[o], av = val_b[o];
    const float4* m4 = (const float4*)mem_s[wid];
#pragma unroll
    for (int k4 = 0; k4 < 16; ++k4) {
        float4 mm = m4[k4];
        ak += dot4(mm, KWP[k4*64 + o]);
        av += dot4(mm, VWP[k4*64 + o]);
    }
    kT[((size_t)b*64 + o)*256 + m] = ak;     // scattered, one-time
    vmat[(size_t)row*64 + o]       = av;     // coalesced
}

// ---------------- main recurrent kernel: 1 wave per batch element ------------
__global__ __launch_bounds__(64, 1) void recurrent_main(
    const int*   __restrict__ seq,
    const float* __restrict__ b_hh,
    const float* __restrict__ query_b,
    const float* __restrict__ head_w,
    const float* __restrict__ head_b,
    const float* __restrict__ kT,
    const float* __restrict__ vmat,
    const float* __restrict__ G,
    const float4* __restrict__ WPhh,
    const float4* __restrict__ WR,
    const float4* __restrict__ QP,
    float* __restrict__ out)
{
    const int b = blockIdx.x;
    const int j = threadIdx.x;

    __shared__ __align__(16) float  h_s[64];
    __shared__ __align__(16) float  q_s[64];
    __shared__ __align__(16) float  ret_s[64];
    __shared__ __align__(16) float4 p_s[64];          // 256 softmax numerators

    // ---- W_hh permanently in registers: 48 float4 = 192 VGPRs ----
    float4 wr0[16], wz0[16], wn0[16];
#pragma unroll
    for (int k4 = 0; k4 < 16; ++k4) {
        wr0[k4] = WPhh[(k4*3 + 0)*64 + j];
        wz0[k4] = WPhh[(k4*3 + 1)*64 + j];
        wn0[k4] = WPhh[(k4*3 + 2)*64 + j];
    }

    float h = 0.f;
    h_s[j] = 0.f;
    const float bhr = b_hh[j], bhz = b_hh[64 + j], bhn = b_hh[128 + j];
    const float qb  = query_b[j];
    __builtin_amdgcn_wave_barrier();

    const float4* kT4  = (const float4*)kT + (size_t)b * 64 * 64;   // [h][m4]
    const float4* v4p  = (const float4*)vmat + (size_t)b * M_ * 16; // [m][o4]
    const int*    seqb = seq + (size_t)b * L_;
    const float4* h4   = (const float4*)h_s;
    const float4* r4   = (const float4*)ret_s;

    const int o4 = j & 15;        // which float4 of the h-dim this lane owns in v-loop
    const int mg = j >> 4;        // m-group 0..3

    for (int c = 0; c < C_; ++c) {
        // ---- prefetch 16 tokens + their G rows (independent of h) ----
        int toks[F_];
#pragma unroll
        for (int t = 0; t < F_; ++t) toks[t] = seqb[c*F_ + t];
        float g0[F_], g1[F_], g2[F_];
#pragma unroll
        for (int t = 0; t < F_; ++t) {
            const float* Gp = G + toks[t]*192;
            g0[t] = Gp[j]; g1[t] = Gp[64 + j]; g2[t] = Gp[128 + j];
        }

        // ---- q = h @ Wq^T + qb ----
        float q = qb;
#pragma unroll
        for (int k4 = 0; k4 < 16; ++k4)
            q += dot4(h4[k4], QP[k4*64 + j]);
        q_s[j] = q;
        __builtin_amdgcn_wave_barrier();

        // ---- scores: lane j owns m = 4j..4j+3; two accumulators ----
        float4 s0 = make_float4(0.f,0.f,0.f,0.f);
        float4 s1 = make_float4(0.f,0.f,0.f,0.f);
#pragma unroll 4
        for (int hh = 0; hh < 64; hh += 2) {
            float  qa = q_s[hh];
            float  qc = q_s[hh + 1];
            float4 ka = kT4[hh*64 + j];
            float4 kc = kT4[(hh + 1)*64 + j];
            s0.x += qa*ka.x; s0.y += qa*ka.y; s0.z += qa*ka.z; s0.w += qa*ka.w;
            s1.x += qc*kc.x; s1.y += qc*kc.y; s1.z += qc*kc.z; s1.w += qc*kc.w;
        }
        const float scale = 0.125f;
        float4 s;
        s.x = (s0.x + s1.x)*scale; s.y = (s0.y + s1.y)*scale;
        s.z = (s0.z + s1.z)*scale; s.w = (s0.w + s1.w)*scale;

        // ---- softmax over 256 (wave allreduce) ----
        float mx = fmaxf(fmaxf(s.x, s.y), fmaxf(s.z, s.w));
#pragma unroll
        for (int o = 32; o > 0; o >>= 1) mx = fmaxf(mx, __shfl_xor(mx, o));
        float4 p;
        p.x = __expf(s.x - mx); p.y = __expf(s.y - mx);
        p.z = __expf(s.z - mx); p.w = __expf(s.w - mx);
        float sum = p.x + p.y + p.z + p.w;
#pragma unroll
        for (int o = 32; o > 0; o >>= 1) sum += __shfl_xor(sum, o);
        float inv = 1.f / sum;
        p_s[j] = p;
        __builtin_amdgcn_wave_barrier();

        // ---- retrieved: lane (mg,o4) accumulates over m = 4i+mg, float4 loads ----
        const float* ps = (const float*)p_s;
        float4 a0 = make_float4(0.f,0.f,0.f,0.f);
        float4 a1 = make_float4(0.f,0.f,0.f,0.f);
#pragma unroll 4
        for (int i = 0; i < 64; i += 2) {
            int m0 = 4*i + mg, m1 = 4*(i + 1) + mg;
            float p0 = ps[m0], p1 = ps[m1];
            float4 v0 = v4p[m0*16 + o4];
            float4 v1 = v4p[m1*16 + o4];
            a0.x += p0*v0.x; a0.y += p0*v0.y; a0.z += p0*v0.z; a0.w += p0*v0.w;
            a1.x += p1*v1.x; a1.y += p1*v1.y; a1.z += p1*v1.z; a1.w += p1*v1.w;
        }
        float4 acc;
        acc.x = (a0.x + a1.x)*inv; acc.y = (a0.y + a1.y)*inv;
        acc.z = (a0.z + a1.z)*inv; acc.w = (a0.w + a1.w)*inv;
        // reduce across the 4 m-groups (lanes j, j^16, j^32, j^48)
#pragma unroll
        for (int o = 16; o <= 32; o <<= 1) {
            acc.x += __shfl_xor(acc.x, o);
            acc.y += __shfl_xor(acc.y, o);
            acc.z += __shfl_xor(acc.z, o);
            acc.w += __shfl_xor(acc.w, o);
        }
        if (j < 16) ((float4*)ret_s)[j] = acc;
        __builtin_amdgcn_wave_barrier();

        // ---- R = W_r @ ret (chunk-constant) ----
        float Rr = 0.f, Rz = 0.f, Rn = 0.f;
#pragma unroll
        for (int k4 = 0; k4 < 16; ++k4) {
            float4 rr = r4[k4];
            Rr += dot4(rr, WR[(k4*3 + 0)*64 + j]);
            Rz += dot4(rr, WR[(k4*3 + 1)*64 + j]);
            Rn += dot4(rr, WR[(k4*3 + 2)*64 + j]);
        }

        // ---- 16 GRU steps: pure VALU (weights in registers, h via LDS bcast) ----
        for (int t = 0; t < F_; ++t) {
            float ghr = bhr, ghz = bhz, ghn = bhn;
#pragma unroll
            for (int k4 = 0; k4 < 16; ++k4) {
                float4 hh = h4[k4];
                ghr += dot4(hh, wr0[k4]);
                ghz += dot4(hh, wz0[k4]);
                ghn += dot4(hh, wn0[k4]);
            }
            float xr = (g0[t] + Rr) + ghr;
            float xz = (g1[t] + Rz) + ghz;
            float r = 1.f / (1.f + __expf(-xr));
            float z = 1.f / (1.f + __expf(-xz));
            float xn = (g2[t] + Rn) + r * ghn;
            float e2 = __expf(-2.f * fabsf(xn));
            float n = copysignf((1.f - e2) / (1.f + e2), xn);
            h = (1.f - z) * n + z * h;
            __builtin_amdgcn_wave_barrier();
            h_s[j] = h;
            __builtin_amdgcn_wave_barrier();
        }
    }

    // ---- head: out[b][j] = h @ head_w[j] + head_b[j] ----
    float o = head_b[j];
#pragma unroll 8
    for (int k = 0; k < 64; ++k)
        o += h_s[k] * head_w[j*64 + k];
    out[(size_t)b*64 + j] = o;
}

extern "C" void kernel_launch(void* const* d_in, const int* in_sizes, int n_in,
                              void* d_out, int out_size, void* d_ws, size_t ws_size,
                              hipStream_t stream) {
    const int*   seq      = (const int*)  d_in[0];
    const float* memory   = (const float*)d_in[1];
    const float* embed_w  = (const float*)d_in[2];
    const float* w_ih     = (const float*)d_in[3];
    const float* w_hh     = (const float*)d_in[4];
    const float* b_ih     = (const float*)d_in[5];
    const float* b_hh     = (const float*)d_in[6];
    const float* key_w    = (const float*)d_in[7];
    const float* key_b    = (const float*)d_in[8];
    const float* val_w    = (const float*)d_in[9];
    const float* val_b    = (const float*)d_in[10];
    const float* query_w  = (const float*)d_in[11];
    const float* query_b  = (const float*)d_in[12];
    const float* head_w   = (const float*)d_in[13];
    const float* head_b   = (const float*)d_in[14];

    float* ws   = (float*)d_ws;
    float* kT   = ws + OFF_KT;
    float* vmat = ws + OFF_V;
    float* G    = ws + OFF_G;
    float4* WPhh = (float4*)(ws + OFF_WPHH);
    float4* WR   = (float4*)(ws + OFF_WR);
    float4* QP   = (float4*)(ws + OFF_QP);
    float4* KWP  = (float4*)(ws + OFF_KWP);
    float4* VWP  = (float4*)(ws + OFF_VWP);

    pack_weights<<<36, 256, 0, stream>>>(w_ih, w_hh, query_w, key_w, val_w,
                                         WPhh, WR, QP, KWP, VWP);
    build_G<<<64, 64, 0, stream>>>(embed_w, w_ih, b_ih, G);
    compute_kv<<<(B_*M_)/4, 256, 0, stream>>>(memory, key_b, val_b, KWP, VWP, kT, vmat);
    recurrent_main<<<B_, 64, 0, stream>>>(seq, b_hh, query_b, head_w, head_b,
                                          kT, vmat, G, WPhh, WR, QP, (float*)d_out);
}

// Round 4
// 5489.451 us; speedup vs baseline: 2.5080x; 1.2383x over previous
//
#include <hip/hip_runtime.h>

// FixedFreqModel: B=512, L=2048, M=256, H=64, VOCAB=64, READ_FREQ=16.
// R4: one wave per batch element; kT + v + QP staged in LDS once per block
// (149 KB, 1 block/CU). WR stays in global (shared across all blocks -> L2
// broadcast-hot). W_hh in VGPRs. Fixes R3's undersized QP/WR LDS regions
// (QP needs 1024 f4, WR needs 3072 f4 -- WR dropped from LDS entirely).

#define B_ 512
#define L_ 2048
#define M_ 256
#define H_ 64
#define C_ 128
#define F_ 16

#define OFF_KT   0u
#define OFF_V    8388608u
#define OFF_G    16777216u
#define OFF_WPHH 16789504u
#define OFF_WR   16801792u
#define OFF_QP   16814080u
#define OFF_KWP  16818176u
#define OFF_VWP  16822272u

// dynamic LDS layout (float4 units)
#define S_KT   0u        // 4096 f4 : kT_s4[hh*64 + m4]
#define S_V    4096u     // 4096 f4 : v_s4[m*16 + o4]
#define S_QP   8192u     // 1024 f4 : qp_s4[k4*64 + j]   (FULL size this time)
#define S_P    9216u     // 64 f4   : softmax numerators
#define S_H    9280u     // 16 f4   (64 floats)
#define S_RET  9296u     // 16 f4
#define S_Q    9312u     // 16 f4
#define SMEM_F4 9328u
#define SMEM_BYTES (SMEM_F4 * 16u)   // 149,248 B

__device__ __forceinline__ float dot4(float4 a, float4 b) {
    return a.x*b.x + a.y*b.y + a.z*b.z + a.w*b.w;
}

// ---------------- pack weights into float4 lane-consecutive layouts ----------
__global__ void pack_weights(const float* __restrict__ w_ih,
                             const float* __restrict__ w_hh,
                             const float* __restrict__ qw,
                             const float* __restrict__ kw,
                             const float* __restrict__ vw,
                             float4* __restrict__ WPhh,
                             float4* __restrict__ WR,
                             float4* __restrict__ QP,
                             float4* __restrict__ KWP,
                             float4* __restrict__ VWP)
{
    int idx = blockIdx.x * 256 + threadIdx.x;
    if (idx < 3072) {                       // WPhh[(k4*3+g)*64+j] = w_hh[(g*64+j)][4k4..]
        int j = idx & 63, kg = idx >> 6, g = kg % 3, k4 = kg / 3;
        const float* s = w_hh + (g*64 + j)*64 + 4*k4;
        WPhh[idx] = make_float4(s[0], s[1], s[2], s[3]);
    } else if (idx < 6144) {                // WR: retrieved half of w_ih (cols 64..127)
        int i = idx - 3072;
        int j = i & 63, kg = i >> 6, g = kg % 3, k4 = kg / 3;
        const float* s = w_ih + (g*64 + j)*128 + 64 + 4*k4;
        WR[i] = make_float4(s[0], s[1], s[2], s[3]);
    } else if (idx < 7168) {                // QP[k4*64+j] = qw[j][4k4..]
        int i = idx - 6144;
        int j = i & 63, k4 = i >> 6;
        const float* s = qw + j*64 + 4*k4;
        QP[i] = make_float4(s[0], s[1], s[2], s[3]);
    } else if (idx < 8192) {
        int i = idx - 7168;
        int j = i & 63, k4 = i >> 6;
        const float* s = kw + j*64 + 4*k4;
        KWP[i] = make_float4(s[0], s[1], s[2], s[3]);
    } else if (idx < 9216) {
        int i = idx - 8192;
        int j = i & 63, k4 = i >> 6;
        const float* s = vw + j*64 + 4*k4;
        VWP[i] = make_float4(s[0], s[1], s[2], s[3]);
    }
}

// ---------------- G[v][o] = sum_k embed[v][k]*w_ih[o][k] + b_ih[o] ----------
__global__ __launch_bounds__(64) void build_G(const float* __restrict__ embed_w,
                                              const float* __restrict__ w_ih,
                                              const float* __restrict__ b_ih,
                                              float* __restrict__ G)
{
    int v = blockIdx.x, j = threadIdx.x;
    __shared__ float e_s[64];
    e_s[j] = embed_w[v*64 + j];
    __syncthreads();
    float a0 = b_ih[j], a1 = b_ih[64 + j], a2 = b_ih[128 + j];
    for (int k = 0; k < 64; ++k) {
        float e = e_s[k];
        a0 += e * w_ih[j*128 + k];
        a1 += e * w_ih[(64 + j)*128 + k];
        a2 += e * w_ih[(128 + j)*128 + k];
    }
    G[v*192 + j]       = a0;
    G[v*192 + 64 + j]  = a1;
    G[v*192 + 128 + j] = a2;
}

// ---------------- k/v precompute: one wave per (b,m) row ---------------------
__global__ __launch_bounds__(256) void compute_kv(const float* __restrict__ memory,
                                                  const float* __restrict__ key_b,
                                                  const float* __restrict__ val_b,
                                                  const float4* __restrict__ KWP,
                                                  const float4* __restrict__ VWP,
                                                  float* __restrict__ kT,
                                                  float* __restrict__ vmat)
{
    int wid = threadIdx.x >> 6;
    int o   = threadIdx.x & 63;
    int row = blockIdx.x * 4 + wid;          // row = b*256 + m
    int b = row >> 8, m = row & 255;
    __shared__ __align__(16) float mem_s[4][64];
    mem_s[wid][o] = memory[(size_t)row * 64 + o];
    __syncthreads();
    float ak = key_b[o], av = val_b[o];
    const float4* m4 = (const float4*)mem_s[wid];
#pragma unroll
    for (int k4 = 0; k4 < 16; ++k4) {
        float4 mm = m4[k4];
        ak += dot4(mm, KWP[k4*64 + o]);
        av += dot4(mm, VWP[k4*64 + o]);
    }
    kT[((size_t)b*64 + o)*256 + m] = ak;     // scattered, one-time
    vmat[(size_t)row*64 + o]       = av;     // coalesced
}

// ---------------- main recurrent kernel: 1 wave per batch element ------------
__global__ __launch_bounds__(64, 1) void recurrent_main(
    const int*   __restrict__ seq,
    const float* __restrict__ b_hh,
    const float* __restrict__ query_b,
    const float* __restrict__ head_w,
    const float* __restrict__ head_b,
    const float* __restrict__ kT,
    const float* __restrict__ vmat,
    const float* __restrict__ G,
    const float4* __restrict__ WPhh,
    const float4* __restrict__ WR,
    const float4* __restrict__ QP,
    float* __restrict__ out)
{
    const int b = blockIdx.x;
    const int j = threadIdx.x;

    extern __shared__ __align__(16) float4 smem[];
    float4* kT_s4 = smem + S_KT;
    float4* v_s4  = smem + S_V;
    float4* qp_s4 = smem + S_QP;
    float4* p_s4  = smem + S_P;
    float*  h_s   = (float*)(smem + S_H);
    float*  ret_s = (float*)(smem + S_RET);
    float*  q_s   = (float*)(smem + S_Q);

    // ---- stage kT, v, QP into LDS (once) ----
    {
        const float4* kTg = (const float4*)kT   + (size_t)b * 4096;
        const float4* vg  = (const float4*)vmat + (size_t)b * 4096;
#pragma unroll
        for (int i = 0; i < 64; ++i) {
            kT_s4[i*64 + j] = kTg[i*64 + j];
            v_s4[i*64 + j]  = vg[i*64 + j];
        }
#pragma unroll
        for (int i = 0; i < 16; ++i) qp_s4[i*64 + j] = QP[i*64 + j];
    }

    // ---- W_hh permanently in registers: 48 float4 = 192 VGPRs ----
    float4 wr0[16], wz0[16], wn0[16];
#pragma unroll
    for (int k4 = 0; k4 < 16; ++k4) {
        wr0[k4] = WPhh[(k4*3 + 0)*64 + j];
        wz0[k4] = WPhh[(k4*3 + 1)*64 + j];
        wn0[k4] = WPhh[(k4*3 + 2)*64 + j];
    }

    float h = 0.f;
    h_s[j] = 0.f;
    const float bhr = b_hh[j], bhz = b_hh[64 + j], bhn = b_hh[128 + j];
    const float qb  = query_b[j];
    __builtin_amdgcn_wave_barrier();

    const int*    seqb = seq + (size_t)b * L_;
    const float4* h4   = (const float4*)h_s;
    const float4* r4   = (const float4*)ret_s;

    const int o4 = j & 15;        // which float4 of the h-dim this lane owns in v-loop
    const int mg = j >> 4;        // m-group 0..3

    for (int c = 0; c < C_; ++c) {
        // ---- prefetch 16 tokens + their G rows (independent of h) ----
        int toks[F_];
#pragma unroll
        for (int t = 0; t < F_; ++t) toks[t] = seqb[c*F_ + t];
        float g0[F_], g1[F_], g2[F_];
#pragma unroll
        for (int t = 0; t < F_; ++t) {
            const float* Gp = G + toks[t]*192;
            g0[t] = Gp[j]; g1[t] = Gp[64 + j]; g2[t] = Gp[128 + j];
        }

        // ---- q = h @ Wq^T + qb ----
        float q = qb;
#pragma unroll
        for (int k4 = 0; k4 < 16; ++k4)
            q += dot4(h4[k4], qp_s4[k4*64 + j]);
        q_s[j] = q;
        __builtin_amdgcn_wave_barrier();

        // ---- scores: lane j owns m = 4j..4j+3; two accumulators ----
        float4 s0 = make_float4(0.f,0.f,0.f,0.f);
        float4 s1 = make_float4(0.f,0.f,0.f,0.f);
#pragma unroll 8
        for (int hh = 0; hh < 64; hh += 2) {
            float  qa = q_s[hh];
            float  qc = q_s[hh + 1];
            float4 ka = kT_s4[hh*64 + j];
            float4 kc = kT_s4[(hh + 1)*64 + j];
            s0.x += qa*ka.x; s0.y += qa*ka.y; s0.z += qa*ka.z; s0.w += qa*ka.w;
            s1.x += qc*kc.x; s1.y += qc*kc.y; s1.z += qc*kc.z; s1.w += qc*kc.w;
        }
        const float scale = 0.125f;
        float4 s;
        s.x = (s0.x + s1.x)*scale; s.y = (s0.y + s1.y)*scale;
        s.z = (s0.z + s1.z)*scale; s.w = (s0.w + s1.w)*scale;

        // ---- softmax over 256 (wave allreduce) ----
        float mx = fmaxf(fmaxf(s.x, s.y), fmaxf(s.z, s.w));
#pragma unroll
        for (int o = 32; o > 0; o >>= 1) mx = fmaxf(mx, __shfl_xor(mx, o));
        float4 p;
        p.x = __expf(s.x - mx); p.y = __expf(s.y - mx);
        p.z = __expf(s.z - mx); p.w = __expf(s.w - mx);
        float sum = p.x + p.y + p.z + p.w;
#pragma unroll
        for (int o = 32; o > 0; o >>= 1) sum += __shfl_xor(sum, o);
        float inv = 1.f / sum;
        p_s4[j] = p;
        __builtin_amdgcn_wave_barrier();

        // ---- retrieved: lane (mg,o4) accumulates over m = 4i+mg, LDS float4 ----
        const float* ps = (const float*)p_s4;
        float4 a0 = make_float4(0.f,0.f,0.f,0.f);
        float4 a1 = make_float4(0.f,0.f,0.f,0.f);
#pragma unroll 8
        for (int i = 0; i < 64; i += 2) {
            int m0 = 4*i + mg, m1 = 4*(i + 1) + mg;
            float p0 = ps[m0], p1 = ps[m1];
            float4 v0 = v_s4[m0*16 + o4];
            float4 v1 = v_s4[m1*16 + o4];
            a0.x += p0*v0.x; a0.y += p0*v0.y; a0.z += p0*v0.z; a0.w += p0*v0.w;
            a1.x += p1*v1.x; a1.y += p1*v1.y; a1.z += p1*v1.z; a1.w += p1*v1.w;
        }
        float4 acc;
        acc.x = (a0.x + a1.x)*inv; acc.y = (a0.y + a1.y)*inv;
        acc.z = (a0.z + a1.z)*inv; acc.w = (a0.w + a1.w)*inv;
        // reduce across the 4 m-groups (lanes j, j^16, j^32, j^48)
#pragma unroll
        for (int o = 16; o <= 32; o <<= 1) {
            acc.x += __shfl_xor(acc.x, o);
            acc.y += __shfl_xor(acc.y, o);
            acc.z += __shfl_xor(acc.z, o);
            acc.w += __shfl_xor(acc.w, o);
        }
        if (j < 16) ((float4*)ret_s)[j] = acc;
        __builtin_amdgcn_wave_barrier();

        // ---- R = W_r @ ret (chunk-constant; WR from global, L2-broadcast) ----
        float Rr = 0.f, Rz = 0.f, Rn = 0.f;
#pragma unroll
        for (int k4 = 0; k4 < 16; ++k4) {
            float4 rr = r4[k4];
            Rr += dot4(rr, WR[(k4*3 + 0)*64 + j]);
            Rz += dot4(rr, WR[(k4*3 + 1)*64 + j]);
            Rn += dot4(rr, WR[(k4*3 + 2)*64 + j]);
        }

        // ---- 16 GRU steps: pure VALU (weights in registers, h via LDS bcast) ----
        for (int t = 0; t < F_; ++t) {
            float ghr = bhr, ghz = bhz, ghn = bhn;
#pragma unroll
            for (int k4 = 0; k4 < 16; ++k4) {
                float4 hh = h4[k4];
                ghr += dot4(hh, wr0[k4]);
                ghz += dot4(hh, wz0[k4]);
                ghn += dot4(hh, wn0[k4]);
            }
            float xr = (g0[t] + Rr) + ghr;
            float xz = (g1[t] + Rz) + ghz;
            float r = 1.f / (1.f + __expf(-xr));
            float z = 1.f / (1.f + __expf(-xz));
            float xn = (g2[t] + Rn) + r * ghn;
            float e2 = __expf(-2.f * fabsf(xn));
            float n = copysignf((1.f - e2) / (1.f + e2), xn);
            h = (1.f - z) * n + z * h;
            __builtin_amdgcn_wave_barrier();
            h_s[j] = h;
            __builtin_amdgcn_wave_barrier();
        }
    }

    // ---- head: out[b][j] = h @ head_w[j] + head_b[j] ----
    float o = head_b[j];
#pragma unroll 8
    for (int k = 0; k < 64; ++k)
        o += h_s[k] * head_w[j*64 + k];
    out[(size_t)b*64 + j] = o;
}

extern "C" void kernel_launch(void* const* d_in, const int* in_sizes, int n_in,
                              void* d_out, int out_size, void* d_ws, size_t ws_size,
                              hipStream_t stream) {
    const int*   seq      = (const int*)  d_in[0];
    const float* memory   = (const float*)d_in[1];
    const float* embed_w  = (const float*)d_in[2];
    const float* w_ih     = (const float*)d_in[3];
    const float* w_hh     = (const float*)d_in[4];
    const float* b_ih     = (const float*)d_in[5];
    const float* b_hh     = (const float*)d_in[6];
    const float* key_w    = (const float*)d_in[7];
    const float* key_b    = (const float*)d_in[8];
    const float* val_w    = (const float*)d_in[9];
    const float* val_b    = (const float*)d_in[10];
    const float* query_w  = (const float*)d_in[11];
    const float* query_b  = (const float*)d_in[12];
    const float* head_w   = (const float*)d_in[13];
    const float* head_b   = (const float*)d_in[14];

    float* ws   = (float*)d_ws;
    float* kT   = ws + OFF_KT;
    float* vmat = ws + OFF_V;
    float* G    = ws + OFF_G;
    float4* WPhh = (float4*)(ws + OFF_WPHH);
    float4* WR   = (float4*)(ws + OFF_WR);
    float4* QP   = (float4*)(ws + OFF_QP);
    float4* KWP  = (float4*)(ws + OFF_KWP);
    float4* VWP  = (float4*)(ws + OFF_VWP);

    static_assert(SMEM_BYTES <= 160*1024, "LDS over 160KB");
    (void)hipFuncSetAttribute((const void*)recurrent_main,
                              hipFuncAttributeMaxDynamicSharedMemorySize,
                              (int)SMEM_BYTES);

    pack_weights<<<36, 256, 0, stream>>>(w_ih, w_hh, query_w, key_w, val_w,
                                         WPhh, WR, QP, KWP, VWP);
    build_G<<<64, 64, 0, stream>>>(embed_w, w_ih, b_ih, G);
    compute_kv<<<(B_*M_)/4, 256, 0, stream>>>(memory, key_b, val_b, KWP, VWP, kT, vmat);
    recurrent_main<<<B_, 64, SMEM_BYTES, stream>>>(seq, b_hh, query_b, head_w, head_b,
                                                   kT, vmat, G, WPhh, WR, QP, (float*)d_out);
}

// Round 5
// 2900.604 us; speedup vs baseline: 4.7464x; 1.8925x over previous
//
#include <hip/hip_runtime.h>
#include <hip/hip_fp16.h>

// FixedFreqModel: B=512, L=2048, M=256, H=64, VOCAB=64, READ_FREQ=16.
// R5: one wave per batch element; kT/v/QP in LDS as fp16 (75.5 KB -> 2
// blocks/CU, single occupancy round). W_hh in VGPRs. G loads software-
// pipelined per GRU step (kills the 48-VGPR prefetch arrays of R4).
// GRU h-reads batched into hreg[16] with dual accumulators per gate.

#define B_ 512
#define L_ 2048
#define M_ 256
#define H_ 64
#define C_ 128
#define F_ 16

// workspace offsets (bytes)
#define WS_KT    0u            // 512*16384 halves = 16 MB
#define WS_V     16777216u     // 16 MB
#define WS_G     33554432u     // 64*192 fp32 = 48 KB
#define WS_WPHH  33603584u     // 3072 float4 = 48 KB
#define WS_WR    33652736u     // 3072 float4 = 48 KB
#define WS_QP    33701888u     // 1024 * 8B (half4) = 8 KB
#define WS_KWP   33710080u     // 1024 float4 = 16 KB
#define WS_VWP   33726464u     // 16 KB

// dynamic LDS layout (bytes)
#define S_KT   0u        // 32768 : kT half [hh][m]   (64 x 256)
#define S_V    32768u    // 32768 : v  half [m][h]    (256 x 64)
#define S_QP   65536u    // 8192  : QP half4 [k4][j]  (16 x 64)
#define S_P    73728u    // 1024  : float4 p_s[64]
#define S_H    74752u    // 256   : h fp32
#define S_RET  75008u    // 256
#define S_Q    75264u    // 256
#define SMEM_BYTES 75520u

__device__ __forceinline__ float dot4(float4 a, float4 b) {
    return a.x*b.x + a.y*b.y + a.z*b.z + a.w*b.w;
}

// ---------------- pack weights -----------------------------------------------
__global__ void pack_weights(const float* __restrict__ w_ih,
                             const float* __restrict__ w_hh,
                             const float* __restrict__ qw,
                             const float* __restrict__ kw,
                             const float* __restrict__ vw,
                             float4* __restrict__ WPhh,
                             float4* __restrict__ WR,
                             __half2* __restrict__ QPh,
                             float4* __restrict__ KWP,
                             float4* __restrict__ VWP)
{
    int idx = blockIdx.x * 256 + threadIdx.x;
    if (idx < 3072) {                       // WPhh[(k4*3+g)*64+j] = w_hh[(g*64+j)][4k4..]
        int j = idx & 63, kg = idx >> 6, g = kg % 3, k4 = kg / 3;
        const float* s = w_hh + (g*64 + j)*64 + 4*k4;
        WPhh[idx] = make_float4(s[0], s[1], s[2], s[3]);
    } else if (idx < 6144) {                // WR: retrieved half of w_ih (cols 64..127)
        int i = idx - 3072;
        int j = i & 63, kg = i >> 6, g = kg % 3, k4 = kg / 3;
        const float* s = w_ih + (g*64 + j)*128 + 64 + 4*k4;
        WR[i] = make_float4(s[0], s[1], s[2], s[3]);
    } else if (idx < 7168) {                // QPh[i*2 .. +1] = half4 of qw[j][4k4..]
        int i = idx - 6144;
        int j = i & 63, k4 = i >> 6;
        const float* s = qw + j*64 + 4*k4;
        QPh[i*2]     = __floats2half2_rn(s[0], s[1]);
        QPh[i*2 + 1] = __floats2half2_rn(s[2], s[3]);
    } else if (idx < 8192) {
        int i = idx - 7168;
        int j = i & 63, k4 = i >> 6;
        const float* s = kw + j*64 + 4*k4;
        KWP[i] = make_float4(s[0], s[1], s[2], s[3]);
    } else if (idx < 9216) {
        int i = idx - 8192;
        int j = i & 63, k4 = i >> 6;
        const float* s = vw + j*64 + 4*k4;
        VWP[i] = make_float4(s[0], s[1], s[2], s[3]);
    }
}

// ---------------- G[v][o] = sum_k embed[v][k]*w_ih[o][k] + b_ih[o] ----------
__global__ __launch_bounds__(64) void build_G(const float* __restrict__ embed_w,
                                              const float* __restrict__ w_ih,
                                              const float* __restrict__ b_ih,
                                              float* __restrict__ G)
{
    int v = blockIdx.x, j = threadIdx.x;
    __shared__ float e_s[64];
    e_s[j] = embed_w[v*64 + j];
    __syncthreads();
    float a0 = b_ih[j], a1 = b_ih[64 + j], a2 = b_ih[128 + j];
    for (int k = 0; k < 64; ++k) {
        float e = e_s[k];
        a0 += e * w_ih[j*128 + k];
        a1 += e * w_ih[(64 + j)*128 + k];
        a2 += e * w_ih[(128 + j)*128 + k];
    }
    G[v*192 + j]       = a0;
    G[v*192 + 64 + j]  = a1;
    G[v*192 + 128 + j] = a2;
}

// ---------------- k/v precompute (fp16 outputs) ------------------------------
__global__ __launch_bounds__(256) void compute_kv(const float* __restrict__ memory,
                                                  const float* __restrict__ key_b,
                                                  const float* __restrict__ val_b,
                                                  const float4* __restrict__ KWP,
                                                  const float4* __restrict__ VWP,
                                                  __half* __restrict__ kT_h,
                                                  __half* __restrict__ v_h)
{
    int wid = threadIdx.x >> 6;
    int o   = threadIdx.x & 63;
    int row = blockIdx.x * 4 + wid;          // row = b*256 + m
    int b = row >> 8, m = row & 255;
    __shared__ __align__(16) float mem_s[4][64];
    mem_s[wid][o] = memory[(size_t)row * 64 + o];
    __syncthreads();
    float ak = key_b[o], av = val_b[o];
    const float4* m4 = (const float4*)mem_s[wid];
#pragma unroll
    for (int k4 = 0; k4 < 16; ++k4) {
        float4 mm = m4[k4];
        ak += dot4(mm, KWP[k4*64 + o]);
        av += dot4(mm, VWP[k4*64 + o]);
    }
    kT_h[((size_t)b*64 + o)*256 + m] = __float2half(ak);  // scattered, one-time
    v_h[(size_t)row*64 + o]          = __float2half(av);  // coalesced
}

__device__ __forceinline__ void cvt4(uint2 raw, float4& out) {
    __half2* hp = (__half2*)&raw;
    float2 a = __half22float2(hp[0]);
    float2 b = __half22float2(hp[1]);
    out.x = a.x; out.y = a.y; out.z = b.x; out.w = b.y;
}

// ---------------- main recurrent kernel: 1 wave per batch element ------------
__global__ __launch_bounds__(64, 1) void recurrent_main(
    const int*   __restrict__ seq,
    const float* __restrict__ b_hh,
    const float* __restrict__ query_b,
    const float* __restrict__ head_w,
    const float* __restrict__ head_b,
    const __half* __restrict__ kT_h,
    const __half* __restrict__ v_h,
    const float* __restrict__ G,
    const float4* __restrict__ WPhh,
    const float4* __restrict__ WR,
    float* __restrict__ out)
{
    const int b = blockIdx.x;
    const int j = threadIdx.x;

    extern __shared__ __align__(16) char smem[];
    const uint2* kT_u2 = (const uint2*)(smem + S_KT);   // [hh*64 + j]  (j = m-quad)
    const uint2* v_u2  = (const uint2*)(smem + S_V);    // [m*16 + o4]
    const uint2* qp_u2 = (const uint2*)(smem + S_QP);   // [k4*64 + j]
    float4* p_s4  = (float4*)(smem + S_P);
    float*  h_s   = (float*)(smem + S_H);
    float*  ret_s = (float*)(smem + S_RET);
    float*  q_s   = (float*)(smem + S_Q);

    // ---- stage kT, v (fp16) and QP into LDS once ----
    {
        const uint4* kTg = (const uint4*)(kT_h + (size_t)b * 16384);
        const uint4* vg  = (const uint4*)(v_h  + (size_t)b * 16384);
        uint4* kTls = (uint4*)(smem + S_KT);
        uint4* vls  = (uint4*)(smem + S_V);
#pragma unroll
        for (int i = 0; i < 32; ++i) {
            kTls[i*64 + j] = kTg[i*64 + j];
            vls[i*64 + j]  = vg[i*64 + j];
        }
        const uint4* qpg = (const uint4*)((const char*)WPhh + (WS_QP - WS_WPHH));
        uint4* qls = (uint4*)(smem + S_QP);
#pragma unroll
        for (int i = 0; i < 8; ++i) qls[i*64 + j] = qpg[i*64 + j];
    }

    // ---- W_hh permanently in registers: 48 float4 = 192 VGPRs ----
    float4 wr0[16], wz0[16], wn0[16];
#pragma unroll
    for (int k4 = 0; k4 < 16; ++k4) {
        wr0[k4] = WPhh[(k4*3 + 0)*64 + j];
        wz0[k4] = WPhh[(k4*3 + 1)*64 + j];
        wn0[k4] = WPhh[(k4*3 + 2)*64 + j];
    }

    float h = 0.f;
    h_s[j] = 0.f;
    const float bhr = b_hh[j], bhz = b_hh[64 + j], bhn = b_hh[128 + j];
    const float qb  = query_b[j];
    __builtin_amdgcn_wave_barrier();

    const int*    seqb = seq + (size_t)b * L_;
    const float4* h4   = (const float4*)h_s;
    const float4* r4   = (const float4*)ret_s;

    const int o4 = j & 15;        // h-quad owned in v-loop
    const int mg = j >> 4;        // m-group 0..3

    for (int c = 0; c < C_; ++c) {
        // ---- tokens (wave-uniform -> SGPRs) ----
        int toks[F_];
#pragma unroll
        for (int t = 0; t < F_; ++t) toks[t] = seqb[c*F_ + t];

        // ---- q = h @ Wq^T + qb  (QP fp16 from LDS) ----
        float q = qb;
#pragma unroll
        for (int k4 = 0; k4 < 16; ++k4) {
            float4 qp; cvt4(qp_u2[k4*64 + j], qp);
            q += dot4(h4[k4], qp);
        }
        q_s[j] = q;
        __builtin_amdgcn_wave_barrier();

        // ---- scores: lane j owns m = 4j..4j+3 (fp16 kT) ----
        float4 s0 = make_float4(0.f,0.f,0.f,0.f);
        float4 s1 = make_float4(0.f,0.f,0.f,0.f);
#pragma unroll 8
        for (int hh = 0; hh < 64; hh += 2) {
            float qa = q_s[hh], qc = q_s[hh + 1];
            float4 ka, kc;
            cvt4(kT_u2[hh*64 + j], ka);
            cvt4(kT_u2[(hh + 1)*64 + j], kc);
            s0.x += qa*ka.x; s0.y += qa*ka.y; s0.z += qa*ka.z; s0.w += qa*ka.w;
            s1.x += qc*kc.x; s1.y += qc*kc.y; s1.z += qc*kc.z; s1.w += qc*kc.w;
        }
        const float scale = 0.125f;
        float4 s;
        s.x = (s0.x + s1.x)*scale; s.y = (s0.y + s1.y)*scale;
        s.z = (s0.z + s1.z)*scale; s.w = (s0.w + s1.w)*scale;

        // ---- softmax over 256 (wave allreduce) ----
        float mx = fmaxf(fmaxf(s.x, s.y), fmaxf(s.z, s.w));
#pragma unroll
        for (int o = 32; o > 0; o >>= 1) mx = fmaxf(mx, __shfl_xor(mx, o));
        float4 p;
        p.x = __expf(s.x - mx); p.y = __expf(s.y - mx);
        p.z = __expf(s.z - mx); p.w = __expf(s.w - mx);
        float sum = p.x + p.y + p.z + p.w;
#pragma unroll
        for (int o = 32; o > 0; o >>= 1) sum += __shfl_xor(sum, o);
        float inv = 1.f / sum;
        p_s4[j] = p;
        __builtin_amdgcn_wave_barrier();

        // ---- retrieved: lane (mg,o4) over m = 4i+mg (fp16 v) ----
        const float* ps = (const float*)p_s4;
        float4 a0 = make_float4(0.f,0.f,0.f,0.f);
        float4 a1 = make_float4(0.f,0.f,0.f,0.f);
#pragma unroll 8
        for (int i = 0; i < 64; i += 2) {
            int m0 = 4*i + mg, m1 = 4*(i + 1) + mg;
            float p0 = ps[m0], p1 = ps[m1];
            float4 v0, v1;
            cvt4(v_u2[m0*16 + o4], v0);
            cvt4(v_u2[m1*16 + o4], v1);
            a0.x += p0*v0.x; a0.y += p0*v0.y; a0.z += p0*v0.z; a0.w += p0*v0.w;
            a1.x += p1*v1.x; a1.y += p1*v1.y; a1.z += p1*v1.z; a1.w += p1*v1.w;
        }
        float4 acc;
        acc.x = (a0.x + a1.x)*inv; acc.y = (a0.y + a1.y)*inv;
        acc.z = (a0.z + a1.z)*inv; acc.w = (a0.w + a1.w)*inv;
#pragma unroll
        for (int o = 16; o <= 32; o <<= 1) {
            acc.x += __shfl_xor(acc.x, o);
            acc.y += __shfl_xor(acc.y, o);
            acc.z += __shfl_xor(acc.z, o);
            acc.w += __shfl_xor(acc.w, o);
        }
        if (j < 16) ((float4*)ret_s)[j] = acc;
        __builtin_amdgcn_wave_barrier();

        // ---- R = W_r @ ret (chunk-constant; WR from global, L2-broadcast) ----
        float Rr = 0.f, Rz = 0.f, Rn = 0.f;
#pragma unroll
        for (int k4 = 0; k4 < 16; ++k4) {
            float4 rr = r4[k4];
            Rr += dot4(rr, WR[(k4*3 + 0)*64 + j]);
            Rz += dot4(rr, WR[(k4*3 + 1)*64 + j]);
            Rn += dot4(rr, WR[(k4*3 + 2)*64 + j]);
        }

        // ---- 16 GRU steps; G loads software-pipelined (2-stage) ----
        float cg0, cg1, cg2;
        {
            const float* Gp = G + toks[0]*192;
            cg0 = Gp[j]; cg1 = Gp[64 + j]; cg2 = Gp[128 + j];
        }
#pragma unroll 1
        for (int t = 0; t < F_; ++t) {
            float ng0 = 0.f, ng1 = 0.f, ng2 = 0.f;
            if (t < F_ - 1) {
                const float* Gn = G + toks[t + 1]*192;
                ng0 = Gn[j]; ng1 = Gn[64 + j]; ng2 = Gn[128 + j];
            }
            // batched LDS reads of h, then pure FMA with 6 accumulators
            float4 hreg[16];
#pragma unroll
            for (int k4 = 0; k4 < 16; ++k4) hreg[k4] = h4[k4];
            float ar0 = bhr, az0 = bhz, an0 = bhn;
            float ar1 = 0.f, az1 = 0.f, an1 = 0.f;
#pragma unroll
            for (int k4 = 0; k4 < 16; k4 += 2) {
                ar0 += dot4(hreg[k4],     wr0[k4]);
                ar1 += dot4(hreg[k4 + 1], wr0[k4 + 1]);
                az0 += dot4(hreg[k4],     wz0[k4]);
                az1 += dot4(hreg[k4 + 1], wz0[k4 + 1]);
                an0 += dot4(hreg[k4],     wn0[k4]);
                an1 += dot4(hreg[k4 + 1], wn0[k4 + 1]);
            }
            float xr = (cg0 + Rr) + (ar0 + ar1);
            float xz = (cg1 + Rz) + (az0 + az1);
            float r = 1.f / (1.f + __expf(-xr));
            float z = 1.f / (1.f + __expf(-xz));
            float xn = (cg2 + Rn) + r * (an0 + an1);
            float e2 = __expf(-2.f * fabsf(xn));
            float n = copysignf((1.f - e2) / (1.f + e2), xn);
            h = (1.f - z) * n + z * h;
            __builtin_amdgcn_wave_barrier();
            h_s[j] = h;
            __builtin_amdgcn_wave_barrier();
            cg0 = ng0; cg1 = ng1; cg2 = ng2;
        }
    }

    // ---- head: out[b][j] = h @ head_w[j] + head_b[j] ----
    float o = head_b[j];
#pragma unroll 8
    for (int k = 0; k < 64; ++k)
        o += h_s[k] * head_w[j*64 + k];
    out[(size_t)b*64 + j] = o;
}

extern "C" void kernel_launch(void* const* d_in, const int* in_sizes, int n_in,
                              void* d_out, int out_size, void* d_ws, size_t ws_size,
                              hipStream_t stream) {
    const int*   seq      = (const int*)  d_in[0];
    const float* memory   = (const float*)d_in[1];
    const float* embed_w  = (const float*)d_in[2];
    const float* w_ih     = (const float*)d_in[3];
    const float* w_hh     = (const float*)d_in[4];
    const float* b_ih     = (const float*)d_in[5];
    const float* b_hh     = (const float*)d_in[6];
    const float* key_w    = (const float*)d_in[7];
    const float* key_b    = (const float*)d_in[8];
    const float* val_w    = (const float*)d_in[9];
    const float* val_b    = (const float*)d_in[10];
    const float* query_w  = (const float*)d_in[11];
    const float* query_b  = (const float*)d_in[12];
    const float* head_w   = (const float*)d_in[13];
    const float* head_b   = (const float*)d_in[14];

    char* ws = (char*)d_ws;
    __half* kT_h  = (__half*)(ws + WS_KT);
    __half* v_h   = (__half*)(ws + WS_V);
    float*  G     = (float*) (ws + WS_G);
    float4* WPhh  = (float4*)(ws + WS_WPHH);
    float4* WR    = (float4*)(ws + WS_WR);
    __half2* QPh  = (__half2*)(ws + WS_QP);
    float4* KWP   = (float4*)(ws + WS_KWP);
    float4* VWP   = (float4*)(ws + WS_VWP);

    (void)hipFuncSetAttribute((const void*)recurrent_main,
                              hipFuncAttributeMaxDynamicSharedMemorySize,
                              (int)SMEM_BYTES);

    pack_weights<<<36, 256, 0, stream>>>(w_ih, w_hh, query_w, key_w, val_w,
                                         WPhh, WR, QPh, KWP, VWP);
    build_G<<<64, 64, 0, stream>>>(embed_w, w_ih, b_ih, G);
    compute_kv<<<(B_*M_)/4, 256, 0, stream>>>(memory, key_b, val_b, KWP, VWP, kT_h, v_h);
    recurrent_main<<<B_, 64, SMEM_BYTES, stream>>>(seq, b_hh, query_b, head_w, head_b,
                                                   kT_h, v_h, G, WPhh, WR, (float*)d_out);
}

// Round 6
// 2683.004 us; speedup vs baseline: 5.1314x; 1.0811x over previous
//
#include <hip/hip_runtime.h>
#include <hip/hip_fp16.h>

// FixedFreqModel: B=512, L=2048, M=256, H=64, VOCAB=64, READ_FREQ=16.
// R6: R5 structure (1 wave/batch, fp16 kT/v/QP in 75.5KB LDS, 2 blocks/CU,
// W_hh in VGPRs) plus:
//  - GRU step loop FULLY unrolled -> toks[] static-indexed -> registers
//    (R5's `#pragma unroll 1` put toks in scratch: per-step scratch-load
//    latency on the G-load chain).
//  - packed fp32 math (v2f -> v_pk_fma_f32) in GRU/R/q matvecs and the
//    attention score/value loops: halves VALU issue.

#define B_ 512
#define L_ 2048
#define M_ 256
#define H_ 64
#define C_ 128
#define F_ 16

typedef float v2f __attribute__((ext_vector_type(2)));

// workspace offsets (bytes)
#define WS_KT    0u            // 512*16384 halves = 16 MB
#define WS_V     16777216u     // 16 MB
#define WS_G     33554432u     // 64*192 fp32 = 48 KB
#define WS_WPHH  33603584u     // 3072 float4 = 48 KB
#define WS_WR    33652736u     // 3072 float4 = 48 KB
#define WS_QP    33701888u     // 1024 * 8B (half4) = 8 KB
#define WS_KWP   33710080u     // 1024 float4 = 16 KB
#define WS_VWP   33726464u     // 16 KB

// dynamic LDS layout (bytes)
#define S_KT   0u        // 32768 : kT half [hh][m]   (64 x 256)
#define S_V    32768u    // 32768 : v  half [m][h]    (256 x 64)
#define S_QP   65536u    // 8192  : QP half4 [k4][j]  (16 x 64)
#define S_P    73728u    // 1024  : float4 p_s[64]
#define S_H    74752u    // 256   : h fp32
#define S_RET  75008u    // 256
#define S_Q    75264u    // 256
#define SMEM_BYTES 75520u

__device__ __forceinline__ float dot4(float4 a, float4 b) {
    return a.x*b.x + a.y*b.y + a.z*b.z + a.w*b.w;
}

// half2-pair -> two v2f
__device__ __forceinline__ void cvt2v(uint2 raw, v2f& lo, v2f& hi) {
    __half2* hp = (__half2*)&raw;
    float2 a = __half22float2(hp[0]);
    float2 b = __half22float2(hp[1]);
    lo[0] = a.x; lo[1] = a.y; hi[0] = b.x; hi[1] = b.y;
}

// ---------------- pack weights -----------------------------------------------
__global__ void pack_weights(const float* __restrict__ w_ih,
                             const float* __restrict__ w_hh,
                             const float* __restrict__ qw,
                             const float* __restrict__ kw,
                             const float* __restrict__ vw,
                             float4* __restrict__ WPhh,
                             float4* __restrict__ WR,
                             __half2* __restrict__ QPh,
                             float4* __restrict__ KWP,
                             float4* __restrict__ VWP)
{
    int idx = blockIdx.x * 256 + threadIdx.x;
    if (idx < 3072) {                       // WPhh[(k4*3+g)*64+j] = w_hh[(g*64+j)][4k4..]
        int j = idx & 63, kg = idx >> 6, g = kg % 3, k4 = kg / 3;
        const float* s = w_hh + (g*64 + j)*64 + 4*k4;
        WPhh[idx] = make_float4(s[0], s[1], s[2], s[3]);
    } else if (idx < 6144) {                // WR: retrieved half of w_ih (cols 64..127)
        int i = idx - 3072;
        int j = i & 63, kg = i >> 6, g = kg % 3, k4 = kg / 3;
        const float* s = w_ih + (g*64 + j)*128 + 64 + 4*k4;
        WR[i] = make_float4(s[0], s[1], s[2], s[3]);
    } else if (idx < 7168) {                // QPh[i*2 .. +1] = half4 of qw[j][4k4..]
        int i = idx - 6144;
        int j = i & 63, k4 = i >> 6;
        const float* s = qw + j*64 + 4*k4;
        QPh[i*2]     = __floats2half2_rn(s[0], s[1]);
        QPh[i*2 + 1] = __floats2half2_rn(s[2], s[3]);
    } else if (idx < 8192) {
        int i = idx - 7168;
        int j = i & 63, k4 = i >> 6;
        const float* s = kw + j*64 + 4*k4;
        KWP[i] = make_float4(s[0], s[1], s[2], s[3]);
    } else if (idx < 9216) {
        int i = idx - 8192;
        int j = i & 63, k4 = i >> 6;
        const float* s = vw + j*64 + 4*k4;
        VWP[i] = make_float4(s[0], s[1], s[2], s[3]);
    }
}

// ---------------- G[v][o] = sum_k embed[v][k]*w_ih[o][k] + b_ih[o] ----------
__global__ __launch_bounds__(64) void build_G(const float* __restrict__ embed_w,
                                              const float* __restrict__ w_ih,
                                              const float* __restrict__ b_ih,
                                              float* __restrict__ G)
{
    int v = blockIdx.x, j = threadIdx.x;
    __shared__ float e_s[64];
    e_s[j] = embed_w[v*64 + j];
    __syncthreads();
    float a0 = b_ih[j], a1 = b_ih[64 + j], a2 = b_ih[128 + j];
    for (int k = 0; k < 64; ++k) {
        float e = e_s[k];
        a0 += e * w_ih[j*128 + k];
        a1 += e * w_ih[(64 + j)*128 + k];
        a2 += e * w_ih[(128 + j)*128 + k];
    }
    G[v*192 + j]       = a0;
    G[v*192 + 64 + j]  = a1;
    G[v*192 + 128 + j] = a2;
}

// ---------------- k/v precompute (fp16 outputs) ------------------------------
__global__ __launch_bounds__(256) void compute_kv(const float* __restrict__ memory,
                                                  const float* __restrict__ key_b,
                                                  const float* __restrict__ val_b,
                                                  const float4* __restrict__ KWP,
                                                  const float4* __restrict__ VWP,
                                                  __half* __restrict__ kT_h,
                                                  __half* __restrict__ v_h)
{
    int wid = threadIdx.x >> 6;
    int o   = threadIdx.x & 63;
    int row = blockIdx.x * 4 + wid;          // row = b*256 + m
    int b = row >> 8, m = row & 255;
    __shared__ __align__(16) float mem_s[4][64];
    mem_s[wid][o] = memory[(size_t)row * 64 + o];
    __syncthreads();
    float ak = key_b[o], av = val_b[o];
    const float4* m4 = (const float4*)mem_s[wid];
#pragma unroll
    for (int k4 = 0; k4 < 16; ++k4) {
        float4 mm = m4[k4];
        ak += dot4(mm, KWP[k4*64 + o]);
        av += dot4(mm, VWP[k4*64 + o]);
    }
    kT_h[((size_t)b*64 + o)*256 + m] = __float2half(ak);  // scattered, one-time
    v_h[(size_t)row*64 + o]          = __float2half(av);  // coalesced
}

// ---------------- main recurrent kernel: 1 wave per batch element ------------
__global__ __launch_bounds__(64, 1) void recurrent_main(
    const int*   __restrict__ seq,
    const float* __restrict__ b_hh,
    const float* __restrict__ query_b,
    const float* __restrict__ head_w,
    const float* __restrict__ head_b,
    const __half* __restrict__ kT_h,
    const __half* __restrict__ v_h,
    const float* __restrict__ G,
    const float4* __restrict__ WPhh,
    const float4* __restrict__ WR,
    float* __restrict__ out)
{
    const int b = blockIdx.x;
    const int j = threadIdx.x;

    extern __shared__ __align__(16) char smem[];
    const uint2* kT_u2 = (const uint2*)(smem + S_KT);   // [hh*64 + j]  (j = m-quad)
    const uint2* v_u2  = (const uint2*)(smem + S_V);    // [m*16 + o4]
    const uint2* qp_u2 = (const uint2*)(smem + S_QP);   // [k4*64 + j]
    float4* p_s4  = (float4*)(smem + S_P);
    float*  h_s   = (float*)(smem + S_H);
    float*  ret_s = (float*)(smem + S_RET);
    float*  q_s   = (float*)(smem + S_Q);

    // ---- stage kT, v (fp16) and QP into LDS once ----
    {
        const uint4* kTg = (const uint4*)(kT_h + (size_t)b * 16384);
        const uint4* vg  = (const uint4*)(v_h  + (size_t)b * 16384);
        uint4* kTls = (uint4*)(smem + S_KT);
        uint4* vls  = (uint4*)(smem + S_V);
#pragma unroll
        for (int i = 0; i < 32; ++i) {
            kTls[i*64 + j] = kTg[i*64 + j];
            vls[i*64 + j]  = vg[i*64 + j];
        }
        const uint4* qpg = (const uint4*)((const char*)WPhh + (WS_QP - WS_WPHH));
        uint4* qls = (uint4*)(smem + S_QP);
#pragma unroll
        for (int i = 0; i < 8; ++i) qls[i*64 + j] = qpg[i*64 + j];
    }

    // ---- W_hh permanently in registers as v2f pairs: 96 v2f = 192 VGPRs ----
    v2f wrv[32], wzv[32], wnv[32];
#pragma unroll
    for (int k4 = 0; k4 < 16; ++k4) {
        float4 a = WPhh[(k4*3 + 0)*64 + j];
        float4 bq = WPhh[(k4*3 + 1)*64 + j];
        float4 cq = WPhh[(k4*3 + 2)*64 + j];
        wrv[2*k4][0] = a.x;  wrv[2*k4][1] = a.y;
        wrv[2*k4+1][0] = a.z; wrv[2*k4+1][1] = a.w;
        wzv[2*k4][0] = bq.x; wzv[2*k4][1] = bq.y;
        wzv[2*k4+1][0] = bq.z; wzv[2*k4+1][1] = bq.w;
        wnv[2*k4][0] = cq.x; wnv[2*k4][1] = cq.y;
        wnv[2*k4+1][0] = cq.z; wnv[2*k4+1][1] = cq.w;
    }

    float h = 0.f;
    h_s[j] = 0.f;
    const float bhr = b_hh[j], bhz = b_hh[64 + j], bhn = b_hh[128 + j];
    const float qb  = query_b[j];
    __builtin_amdgcn_wave_barrier();

    const int*    seqb = seq + (size_t)b * L_;
    const float4* h4   = (const float4*)h_s;
    const float4* r4   = (const float4*)ret_s;
    const float4* q_sf4 = (const float4*)q_s;

    const int o4 = j & 15;        // h-quad owned in v-loop
    const int mg = j >> 4;        // m-group 0..3

    for (int c = 0; c < C_; ++c) {
        // ---- tokens: fully static after unroll -> stay in VGPRs ----
        int toks[F_];
#pragma unroll
        for (int t = 0; t < F_; ++t) toks[t] = seqb[c*F_ + t];

        // ---- q = h @ Wq^T + qb  (QP fp16 from LDS, packed fma) ----
        {
            v2f qa = {qb, 0.f}, qc = {0.f, 0.f};
#pragma unroll
            for (int k4 = 0; k4 < 16; ++k4) {
                float4 hh = h4[k4];
                v2f hA; hA[0] = hh.x; hA[1] = hh.y;
                v2f hB; hB[0] = hh.z; hB[1] = hh.w;
                v2f plo, phi; cvt2v(qp_u2[k4*64 + j], plo, phi);
                qa += hA * plo;
                qc += hB * phi;
            }
            q_s[j] = (qa[0] + qc[0]) + (qa[1] + qc[1]);
        }
        __builtin_amdgcn_wave_barrier();

        // ---- scores: lane j owns m = 4j..4j+3 (fp16 kT, packed) ----
        v2f s01a = {0.f,0.f}, s23a = {0.f,0.f};
        v2f s01b = {0.f,0.f}, s23b = {0.f,0.f};
#pragma unroll 4
        for (int hq = 0; hq < 16; ++hq) {
            float4 qq = q_sf4[hq];
            v2f k0l,k0h,k1l,k1h,k2l,k2h,k3l,k3h;
            cvt2v(kT_u2[(4*hq+0)*64 + j], k0l, k0h);
            cvt2v(kT_u2[(4*hq+1)*64 + j], k1l, k1h);
            cvt2v(kT_u2[(4*hq+2)*64 + j], k2l, k2h);
            cvt2v(kT_u2[(4*hq+3)*64 + j], k3l, k3h);
            s01a += k0l * qq.x; s23a += k0h * qq.x;
            s01b += k1l * qq.y; s23b += k1h * qq.y;
            s01a += k2l * qq.z; s23a += k2h * qq.z;
            s01b += k3l * qq.w; s23b += k3h * qq.w;
        }
        const float scale = 0.125f;
        float4 s;
        s.x = (s01a[0] + s01b[0]) * scale;
        s.y = (s01a[1] + s01b[1]) * scale;
        s.z = (s23a[0] + s23b[0]) * scale;
        s.w = (s23a[1] + s23b[1]) * scale;

        // ---- softmax over 256 (wave allreduce) ----
        float mx = fmaxf(fmaxf(s.x, s.y), fmaxf(s.z, s.w));
#pragma unroll
        for (int o = 32; o > 0; o >>= 1) mx = fmaxf(mx, __shfl_xor(mx, o));
        float4 p;
        p.x = __expf(s.x - mx); p.y = __expf(s.y - mx);
        p.z = __expf(s.z - mx); p.w = __expf(s.w - mx);
        float sum = p.x + p.y + p.z + p.w;
#pragma unroll
        for (int o = 32; o > 0; o >>= 1) sum += __shfl_xor(sum, o);
        float inv = 1.f / sum;
        p_s4[j] = p;
        __builtin_amdgcn_wave_barrier();

        // ---- retrieved: lane (mg,o4) over m = 4i+mg (fp16 v, packed) ----
        const float* ps = (const float*)p_s4;
        v2f aA0 = {0.f,0.f}, aB0 = {0.f,0.f};
        v2f aA1 = {0.f,0.f}, aB1 = {0.f,0.f};
#pragma unroll 8
        for (int i = 0; i < 64; i += 2) {
            int m0 = 4*i + mg, m1 = 4*(i + 1) + mg;
            float p0 = ps[m0], p1 = ps[m1];
            v2f v0l, v0h, v1l, v1h;
            cvt2v(v_u2[m0*16 + o4], v0l, v0h);
            cvt2v(v_u2[m1*16 + o4], v1l, v1h);
            aA0 += v0l * p0; aB0 += v0h * p0;
            aA1 += v1l * p1; aB1 += v1h * p1;
        }
        float4 acc;
        acc.x = (aA0[0] + aA1[0]) * inv;
        acc.y = (aA0[1] + aA1[1]) * inv;
        acc.z = (aB0[0] + aB1[0]) * inv;
        acc.w = (aB0[1] + aB1[1]) * inv;
#pragma unroll
        for (int o = 16; o <= 32; o <<= 1) {
            acc.x += __shfl_xor(acc.x, o);
            acc.y += __shfl_xor(acc.y, o);
            acc.z += __shfl_xor(acc.z, o);
            acc.w += __shfl_xor(acc.w, o);
        }
        if (j < 16) ((float4*)ret_s)[j] = acc;
        __builtin_amdgcn_wave_barrier();

        // ---- R = W_r @ ret (chunk-constant; WR from global, packed) ----
        float Rr, Rz, Rn;
        {
            v2f r2 = {0.f,0.f}, z2 = {0.f,0.f}, n2 = {0.f,0.f};
#pragma unroll
            for (int k4 = 0; k4 < 16; ++k4) {
                float4 rr = r4[k4];
                v2f rA; rA[0] = rr.x; rA[1] = rr.y;
                v2f rB; rB[0] = rr.z; rB[1] = rr.w;
                float4 w0 = WR[(k4*3 + 0)*64 + j];
                float4 w1 = WR[(k4*3 + 1)*64 + j];
                float4 w2 = WR[(k4*3 + 2)*64 + j];
                v2f t;
                t[0] = w0.x; t[1] = w0.y; r2 += rA * t;
                t[0] = w0.z; t[1] = w0.w; r2 += rB * t;
                t[0] = w1.x; t[1] = w1.y; z2 += rA * t;
                t[0] = w1.z; t[1] = w1.w; z2 += rB * t;
                t[0] = w2.x; t[1] = w2.y; n2 += rA * t;
                t[0] = w2.z; t[1] = w2.w; n2 += rB * t;
            }
            Rr = r2[0] + r2[1]; Rz = z2[0] + z2[1]; Rn = n2[0] + n2[1];
        }

        // ---- 16 GRU steps, FULLY UNROLLED; G software-pipelined ----
        float cg0, cg1, cg2;
        {
            const float* Gp = G + toks[0]*192;
            cg0 = Gp[j]; cg1 = Gp[64 + j]; cg2 = Gp[128 + j];
        }
#pragma unroll
        for (int t = 0; t < F_; ++t) {
            float ng0 = 0.f, ng1 = 0.f, ng2 = 0.f;
            if (t + 1 < F_) {
                const float* Gn = G + toks[t + 1]*192;   // static index: registers
                ng0 = Gn[j]; ng1 = Gn[64 + j]; ng2 = Gn[128 + j];
            }
            v2f ar0 = {bhr, 0.f}, ar1 = {0.f, 0.f};
            v2f az0 = {bhz, 0.f}, az1 = {0.f, 0.f};
            v2f an0 = {bhn, 0.f}, an1 = {0.f, 0.f};
#pragma unroll
            for (int k4 = 0; k4 < 16; ++k4) {
                float4 hh = h4[k4];
                v2f hA; hA[0] = hh.x; hA[1] = hh.y;
                v2f hB; hB[0] = hh.z; hB[1] = hh.w;
                ar0 += hA * wrv[2*k4];
                ar1 += hB * wrv[2*k4+1];
                az0 += hA * wzv[2*k4];
                az1 += hB * wzv[2*k4+1];
                an0 += hA * wnv[2*k4];
                an1 += hB * wnv[2*k4+1];
            }
            float ghr = (ar0[0] + ar1[0]) + (ar0[1] + ar1[1]);
            float ghz = (az0[0] + az1[0]) + (az0[1] + az1[1]);
            float ghn = (an0[0] + an1[0]) + (an0[1] + an1[1]);
            float xr = (cg0 + Rr) + ghr;
            float xz = (cg1 + Rz) + ghz;
            float r = 1.f / (1.f + __expf(-xr));
            float z = 1.f / (1.f + __expf(-xz));
            float xn = (cg2 + Rn) + r * ghn;
            float e2 = __expf(-2.f * fabsf(xn));
            float n = copysignf((1.f - e2) / (1.f + e2), xn);
            h = (1.f - z) * n + z * h;
            __builtin_amdgcn_wave_barrier();
            h_s[j] = h;
            __builtin_amdgcn_wave_barrier();
            cg0 = ng0; cg1 = ng1; cg2 = ng2;
        }
    }

    // ---- head: out[b][j] = h @ head_w[j] + head_b[j] ----
    float o = head_b[j];
#pragma unroll 8
    for (int k = 0; k < 64; ++k)
        o += h_s[k] * head_w[j*64 + k];
    out[(size_t)b*64 + j] = o;
}

extern "C" void kernel_launch(void* const* d_in, const int* in_sizes, int n_in,
                              void* d_out, int out_size, void* d_ws, size_t ws_size,
                              hipStream_t stream) {
    const int*   seq      = (const int*)  d_in[0];
    const float* memory   = (const float*)d_in[1];
    const float* embed_w  = (const float*)d_in[2];
    const float* w_ih     = (const float*)d_in[3];
    const float* w_hh     = (const float*)d_in[4];
    const float* b_ih     = (const float*)d_in[5];
    const float* b_hh     = (const float*)d_in[6];
    const float* key_w    = (const float*)d_in[7];
    const float* key_b    = (const float*)d_in[8];
    const float* val_w    = (const float*)d_in[9];
    const float* val_b    = (const float*)d_in[10];
    const float* query_w  = (const float*)d_in[11];
    const float* query_b  = (const float*)d_in[12];
    const float* head_w   = (const float*)d_in[13];
    const float* head_b   = (const float*)d_in[14];

    char* ws = (char*)d_ws;
    __half* kT_h  = (__half*)(ws + WS_KT);
    __half* v_h   = (__half*)(ws + WS_V);
    float*  G     = (float*) (ws + WS_G);
    float4* WPhh  = (float4*)(ws + WS_WPHH);
    float4* WR    = (float4*)(ws + WS_WR);
    __half2* QPh  = (__half2*)(ws + WS_QP);
    float4* KWP   = (float4*)(ws + WS_KWP);
    float4* VWP   = (float4*)(ws + WS_VWP);

    (void)hipFuncSetAttribute((const void*)recurrent_main,
                              hipFuncAttributeMaxDynamicSharedMemorySize,
                              (int)SMEM_BYTES);

    pack_weights<<<36, 256, 0, stream>>>(w_ih, w_hh, query_w, key_w, val_w,
                                         WPhh, WR, QPh, KWP, VWP);
    build_G<<<64, 64, 0, stream>>>(embed_w, w_ih, b_ih, G);
    compute_kv<<<(B_*M_)/4, 256, 0, stream>>>(memory, key_b, val_b, KWP, VWP, kT_h, v_h);
    recurrent_main<<<B_, 64, SMEM_BYTES, stream>>>(seq, b_hh, query_b, head_w, head_b,
                                                   kT_h, v_h, G, WPhh, WR, (float*)d_out);
}